// Round 3
// baseline (904.650 us; speedup 1.0000x reference)
//
#include <hip/hip_runtime.h>

#define NG 8   // graphs

typedef _Float16 half8 __attribute__((ext_vector_type(8)));
typedef float    f32x4 __attribute__((ext_vector_type(4)));

// ---------------- casts ----------------

__global__ __launch_bounds__(256)
void k_cast16(const float* __restrict__ in, _Float16* __restrict__ out, int n8) {
    int i = blockIdx.x * 256 + threadIdx.x;
    if (i < n8) {
        const float4 a = *(const float4*)(in + (size_t)i * 8);
        const float4 b = *(const float4*)(in + (size_t)i * 8 + 4);
        half8 o;
        o[0] = (_Float16)a.x; o[1] = (_Float16)a.y; o[2] = (_Float16)a.z; o[3] = (_Float16)a.w;
        o[4] = (_Float16)b.x; o[5] = (_Float16)b.y; o[6] = (_Float16)b.z; o[7] = (_Float16)b.w;
        *(half8*)(out + (size_t)i * 8) = o;
    }
}

// ---------------- CSR build ----------------

__global__ __launch_bounds__(256)
void k_deg(const int* __restrict__ dst, int* __restrict__ deg, int E) {
    int i = blockIdx.x * 256 + threadIdx.x;
    if (i < E) atomicAdd(&deg[dst[i]], 1);
}

__global__ __launch_bounds__(1024)
void k_scan_a(const int* __restrict__ deg, int* __restrict__ incl,
              int* __restrict__ bsum, int n) {
    __shared__ int s[1024];
    int t = threadIdx.x;
    int base = blockIdx.x * 1024;
    int v = (base + t < n) ? deg[base + t] : 0;
    s[t] = v;
    __syncthreads();
    for (int off = 1; off < 1024; off <<= 1) {
        int x = 0;
        if (t >= off) x = s[t - off];
        __syncthreads();
        if (t >= off) s[t] += x;
        __syncthreads();
    }
    if (base + t < n) incl[base + t] = s[t];
    if (t == 1023) bsum[blockIdx.x] = s[1023];
}

__global__ void k_scan_b(int* bsum, int nb) {
    if (threadIdx.x == 0 && blockIdx.x == 0) {
        int run = 0;
        for (int i = 0; i < nb; ++i) { int v = bsum[i]; bsum[i] = run; run += v; }
    }
}

__global__ __launch_bounds__(256)
void k_scan_c(const int* __restrict__ incl, const int* __restrict__ deg,
              const int* __restrict__ bsum, int* __restrict__ rowp, int n) {
    int i = blockIdx.x * 256 + threadIdx.x;
    if (i < n) rowp[i] = incl[i] - deg[i] + bsum[i >> 10];
}

__global__ __launch_bounds__(256)
void k_scatter(const int* __restrict__ src, const int* __restrict__ dst,
               const int* __restrict__ rowp, int* __restrict__ cur,
               int* __restrict__ ss, int E) {
    int i = blockIdx.x * 256 + threadIdx.x;
    if (i < E) {
        int d = dst[i];
        int pos = rowp[d] + atomicAdd(&cur[d], 1);
        ss[pos] = src[i];
    }
}

// ---------------- aggregation (fp16 rows, fp32 accum), fused BN-apply+ReLU ----------------
// h_eff(u) = AFFINE ? relu(sc*z[u]+sh) : z[u];  out = (1+eps)*h_eff(v) + sum_u h_eff(u)

template<int K, bool AFFINE>
__global__ __launch_bounds__(256)
void k_agg16(const _Float16* __restrict__ h, const int* __restrict__ rowp,
             const int* __restrict__ deg, const int* __restrict__ ss,
             const float* __restrict__ eps, const float* __restrict__ scp,
             const float* __restrict__ shp, _Float16* __restrict__ z, int n) {
    constexpr int TPN = K / 8;       // threads per node (16B lanes)
    constexpr int NPB = 256 / TPN;
    int node = blockIdx.x * NPB + threadIdx.x / TPN;
    int lane = threadIdx.x % TPN;
    if (node >= n) return;
    float e1 = 1.0f + eps[0];
    const int c0 = lane * 8;
    float sc[8], sh[8];
    if (AFFINE) {
#pragma unroll
        for (int e = 0; e < 8; ++e) { sc[e] = scp[c0 + e]; sh[e] = shp[c0 + e]; }
    }
    size_t base = (size_t)node * K + c0;
    half8 v = *(const half8*)(h + base);
    float a[8];
#pragma unroll
    for (int e = 0; e < 8; ++e) {
        float f = (float)v[e];
        if (AFFINE) f = fmaxf(f * sc[e] + sh[e], 0.0f);
        a[e] = f * e1;
    }
    int s  = rowp[node];
    int dn = deg[node];
    int j = 0;
    for (; j + 2 <= dn; j += 2) {
        int u0 = ss[s + j], u1 = ss[s + j + 1];
        half8 h0 = *(const half8*)(h + (size_t)u0 * K + c0);
        half8 h1 = *(const half8*)(h + (size_t)u1 * K + c0);
#pragma unroll
        for (int e = 0; e < 8; ++e) {
            float f0 = (float)h0[e], f1 = (float)h1[e];
            if (AFFINE) {
                f0 = fmaxf(f0 * sc[e] + sh[e], 0.0f);
                f1 = fmaxf(f1 * sc[e] + sh[e], 0.0f);
            }
            a[e] += f0 + f1;
        }
    }
    if (j < dn) {
        int u = ss[s + j];
        half8 hv = *(const half8*)(h + (size_t)u * K + c0);
#pragma unroll
        for (int e = 0; e < 8; ++e) {
            float f = (float)hv[e];
            if (AFFINE) f = fmaxf(f * sc[e] + sh[e], 0.0f);
            a[e] += f;
        }
    }
    half8 o;
#pragma unroll
    for (int e = 0; e < 8; ++e) o[e] = (_Float16)a[e];
    *(half8*)(z + base) = o;
}

// ---------------- MFMA GEMM: C = (relu)(A @ W^T + bias), full-M tile ----------------
// A: [n x K] fp16 row-major; W: [M x K] fp16 row-major. BM=128, BN=M, BK=64.
// 512 threads (8 waves, 2x4 wave grid). LDS XOR swizzle kbyte ^= (row&7)<<4.
// Coalesced epilogue via per-wave LDS transpose; optional fused BN-stats.

template<int M, bool RELU, bool STATS>
__global__ __launch_bounds__(512, 4)
void k_gemmf(const _Float16* __restrict__ A, const _Float16* __restrict__ W,
             const float* __restrict__ bias, _Float16* __restrict__ C,
             float* __restrict__ stats, int n, int K) {
    constexpr int FN   = M / 64;     // frags per wave in N (4 or 2)
    constexpr int BISS = M / 64;     // B staging issues (64 rows each)
    __shared__ char smem[16384 + M * 128];
    char* As = smem;
    char* Bs = smem + 16384;
    const int tid  = threadIdx.x;
    const int lane = tid & 63;
    const int wid  = tid >> 6;       // 0..7
    const int wr   = wid >> 2;       // 0..1
    const int wc   = wid & 3;        // 0..3
    const int brow = blockIdx.x * 128;
    const int srow = tid >> 3;       // 0..63
    const int spk  = (tid & 7) << 4; // phys kbyte 0..112

    f32x4 acc[4][FN];
#pragma unroll
    for (int m = 0; m < 4; ++m)
#pragma unroll
        for (int nn = 0; nn < FN; ++nn) acc[m][nn] = (f32x4){0.f, 0.f, 0.f, 0.f};

    uint4 ar[2], br[BISS];
    const int nk = K >> 6;

    // prefetch t=0
#pragma unroll
    for (int i = 0; i < 2; ++i) {
        int row = i * 64 + srow;
        int lk  = spk ^ ((row & 7) << 4);
        int ga  = brow + row; if (ga > n - 1) ga = n - 1;
        ar[i] = *(const uint4*)((const char*)A + ((size_t)ga * K) * 2 + lk);
    }
#pragma unroll
    for (int i = 0; i < BISS; ++i) {
        int row = i * 64 + srow;
        int lk  = spk ^ ((row & 7) << 4);
        br[i] = *(const uint4*)((const char*)W + ((size_t)row * K) * 2 + lk);
    }

    for (int t = 0; t < nk; ++t) {
        __syncthreads();
#pragma unroll
        for (int i = 0; i < 2; ++i)
            *(uint4*)(As + (i * 64 + srow) * 128 + spk) = ar[i];
#pragma unroll
        for (int i = 0; i < BISS; ++i)
            *(uint4*)(Bs + (i * 64 + srow) * 128 + spk) = br[i];
        __syncthreads();
        if (t + 1 < nk) {
            int k0 = (t + 1) << 6;
#pragma unroll
            for (int i = 0; i < 2; ++i) {
                int row = i * 64 + srow;
                int lk  = spk ^ ((row & 7) << 4);
                int ga  = brow + row; if (ga > n - 1) ga = n - 1;
                ar[i] = *(const uint4*)((const char*)A + ((size_t)ga * K + k0) * 2 + lk);
            }
#pragma unroll
            for (int i = 0; i < BISS; ++i) {
                int row = i * 64 + srow;
                int lk  = spk ^ ((row & 7) << 4);
                br[i] = *(const uint4*)((const char*)W + ((size_t)row * K + k0) * 2 + lk);
            }
        }
#pragma unroll
        for (int kk = 0; kk < 2; ++kk) {
            const int kb = kk * 64 + (lane >> 4) * 16;
            half8 af[4], bf[FN];
#pragma unroll
            for (int m = 0; m < 4; ++m) {
                int rowA = wr * 64 + m * 16 + (lane & 15);
                af[m] = *(const half8*)(As + rowA * 128 + (kb ^ ((rowA & 7) << 4)));
            }
#pragma unroll
            for (int nn = 0; nn < FN; ++nn) {
                int rowB = wc * (FN * 16) + nn * 16 + (lane & 15);
                bf[nn] = *(const half8*)(Bs + rowB * 128 + (kb ^ ((rowB & 7) << 4)));
            }
#pragma unroll
            for (int m = 0; m < 4; ++m)
#pragma unroll
                for (int nn = 0; nn < FN; ++nn)
                    acc[m][nn] = __builtin_amdgcn_mfma_f32_16x16x32_f16(af[m], bf[nn], acc[m][nn], 0, 0, 0);
        }
    }

    __syncthreads();   // all waves done reading As/Bs; smem repurposed as transpose buf
    char* tb = smem + wid * 2304;           // per-wave [16][72] fp16, 144 B row stride
    const int colbase = wc * (FN * 16);
    float bb[FN];
#pragma unroll
    for (int nn = 0; nn < FN; ++nn) bb[nn] = bias[colbase + nn * 16 + (lane & 15)];
    constexpr int GRP = FN * 2;             // 8-col groups per wave tile (8 or 4)
    constexpr int RPI = 64 / GRP;           // rows per read iter (8 or 16)
    constexpr int NIT = 16 / RPI;           // read iters per m-chunk (2 or 1)
    const int g   = lane & (GRP - 1);
    const int rl  = lane / GRP;
    const int rcol = colbase + g * 8;
    const int rowbase = brow + wr * 64;
    float s[8], s2[8];
    if (STATS) {
#pragma unroll
        for (int e = 0; e < 8; ++e) { s[e] = 0.f; s2[e] = 0.f; }
    }
#pragma unroll
    for (int m = 0; m < 4; ++m) {
#pragma unroll
        for (int nn = 0; nn < FN; ++nn)
#pragma unroll
            for (int j = 0; j < 4; ++j) {
                float v = acc[m][nn][j] + bb[nn];
                if (RELU) v = fmaxf(v, 0.0f);
                *(_Float16*)(tb + ((lane >> 4) * 4 + j) * 144 + (nn * 16 + (lane & 15)) * 2) = (_Float16)v;
            }
        // per-wave LDS; DS ops complete in order within a wave (compiler inserts lgkmcnt)
#pragma unroll
        for (int it = 0; it < NIT; ++it) {
            int lr = it * RPI + rl;
            int grow = rowbase + m * 16 + lr;
            half8 v = *(const half8*)(tb + lr * 144 + g * 16);
            if (grow < n) {
                *(half8*)(C + (size_t)grow * M + rcol) = v;
                if (STATS) {
#pragma unroll
                    for (int e = 0; e < 8; ++e) { float f = (float)v[e]; s[e] += f; s2[e] += f * f; }
                }
            }
        }
    }
    if (STATS) {
#pragma unroll
        for (int e = 0; e < 8; ++e) {
            for (int mk = GRP; mk < 64; mk <<= 1) {
                s[e]  += __shfl_xor(s[e],  mk, 64);
                s2[e] += __shfl_xor(s2[e], mk, 64);
            }
        }
        if (lane < GRP) {
#pragma unroll
            for (int e = 0; e < 8; ++e) {
                atomicAdd(&stats[rcol + e],     s[e]);
                atomicAdd(&stats[M + rcol + e], s2[e]);
            }
        }
    }
}

// ---------------- BN prep ----------------

__global__ void k_bnprep(float* __restrict__ stats, const float* __restrict__ gamma,
                         const float* __restrict__ beta, int n, int M) {
    int c = threadIdx.x;
    if (c < M) {
        float invN = 1.0f / (float)n;
        float mean = stats[c] * invN;
        float var  = stats[M + c] * invN - mean * mean;
        float sc   = rsqrtf(var + 1e-5f) * gamma[c];
        stats[2 * M + c] = sc;
        stats[3 * M + c] = beta[c] - mean * sc;
    }
}

// ---------------- graph readout (fused final BN) ----------------

__global__ __launch_bounds__(256)
void k_readout_bn(const _Float16* __restrict__ z, const float* __restrict__ stats,
                  const int* __restrict__ gid, float* __restrict__ gsum,
                  int* __restrict__ gcnt, int n) {
    __shared__ float ls[NG * 128];
    __shared__ int   lc[NG];
    for (int i = threadIdx.x; i < NG * 128; i += 256) ls[i] = 0.0f;
    if (threadIdx.x < NG) lc[threadIdx.x] = 0;
    __syncthreads();
    int c  = threadIdx.x & 127;
    int ro = threadIdx.x >> 7;   // 0 or 1
    const float sc = stats[2 * 128 + c];
    const float sh = stats[3 * 128 + c];
    for (int r = blockIdx.x * 2 + ro; r < n; r += gridDim.x * 2) {
        int g = gid[r];
        float v = (float)z[(size_t)r * 128 + c] * sc + sh;
        atomicAdd(&ls[g * 128 + c], v);
        if (c == 0) atomicAdd(&lc[g], 1);
    }
    __syncthreads();
    for (int i = threadIdx.x; i < NG * 128; i += 256) atomicAdd(&gsum[i], ls[i]);
    if (threadIdx.x < NG) atomicAdd(&gcnt[threadIdx.x], lc[threadIdx.x]);
}

__global__ void k_final(const float* __restrict__ gsum, const int* __restrict__ gcnt,
                        float* __restrict__ out) {
    int i = blockIdx.x * 256 + threadIdx.x;
    if (i < NG * 128) {
        int g = i >> 7;
        out[i] = gsum[i] / fmaxf((float)gcnt[g], 1.0f);
    }
}

// ---------------- host ----------------

extern "C" void kernel_launch(void* const* d_in, const int* in_sizes, int n_in,
                              void* d_out, int out_size, void* d_ws, size_t ws_size,
                              hipStream_t stream) {
    const float* x   = (const float*)d_in[0];
    const int*   src = (const int*)d_in[1];
    const int*   dst = (const int*)d_in[2];
    const int*   gid = (const int*)d_in[3];
    const int n = in_sizes[0] / 128;
    const int E = in_sizes[1];

    auto align = [](size_t o) { return (o + 255) & ~(size_t)255; };
    char* ws = (char*)d_ws;
    size_t off = 0;
    const size_t SZ_H  = align((size_t)n * 256 * sizeof(_Float16));
    const size_t SZ_I  = align((size_t)n * sizeof(int));

    _Float16* h0 = (_Float16*)(ws + off); off += align((size_t)n * 128 * sizeof(_Float16));
    _Float16* P0 = (_Float16*)(ws + off); off += SZ_H;
    _Float16* P1 = (_Float16*)(ws + off); off += SZ_H;
    _Float16* P2 = (_Float16*)(ws + off); off += SZ_H;
    int*   deg  = (int*)(ws + off);   off += SZ_I;
    int*   incl = (int*)(ws + off);   off += SZ_I;
    int*   rowp = (int*)(ws + off);   off += SZ_I;
    int*   cur  = (int*)(ws + off);   off += SZ_I;
    int*   bsum = (int*)(ws + off);   off += 256 * sizeof(int);
    int*   ss   = (int*)(ws + off);   off += align((size_t)E * sizeof(int));
    float* stats= (float*)(ws + off); off += align(4 * 256 * sizeof(float));
    float* gsum = (float*)(ws + off); off += align(NG * 128 * sizeof(float));
    int*   gcnt = (int*)(ws + off);   off += align(NG * sizeof(int));
    _Float16* wh[6];
    for (int i = 0; i < 6; ++i) { wh[i] = (_Float16*)(ws + off); off += align(65536 * sizeof(_Float16)); }

    const int Ks[3]    = {128, 256, 256};
    const int Mids[3]  = {256, 256, 128};
    const int Mouts[3] = {256, 256, 128};

    // ---- casts ----
    k_cast16<<<(n * 128 / 8 + 255) / 256, 256, 0, stream>>>(x, h0, n * 128 / 8);
    for (int L = 0; L < 3; ++L) {
        const int base = 4 + 7 * L;
        int n1 = Mids[L] * Ks[L];
        int n2 = Mouts[L] * Mids[L];
        k_cast16<<<(n1 / 8 + 255) / 256, 256, 0, stream>>>((const float*)d_in[base + 0], wh[2 * L + 0], n1 / 8);
        k_cast16<<<(n2 / 8 + 255) / 256, 256, 0, stream>>>((const float*)d_in[base + 2], wh[2 * L + 1], n2 / 8);
    }

    // ---- CSR build (dst-keyed) ----
    hipMemsetAsync(deg, 0, (size_t)n * sizeof(int), stream);
    k_deg<<<(E + 255) / 256, 256, 0, stream>>>(dst, deg, E);
    int nb = (n + 1023) / 1024;
    k_scan_a<<<nb, 1024, 0, stream>>>(deg, incl, bsum, n);
    k_scan_b<<<1, 1, 0, stream>>>(bsum, nb);
    k_scan_c<<<(n + 255) / 256, 256, 0, stream>>>(incl, deg, bsum, rowp, n);
    hipMemsetAsync(cur, 0, (size_t)n * sizeof(int), stream);
    k_scatter<<<(E + 255) / 256, 256, 0, stream>>>(src, dst, rowp, cur, ss, E);

    // ---- layers ----
    const int gx = (n + 127) / 128;
    for (int L = 0; L < 3; ++L) {
        const int base = 4 + 7 * L;
        const float* b1    = (const float*)d_in[base + 1];
        const float* b2    = (const float*)d_in[base + 3];
        const float* eps   = (const float*)d_in[base + 4];
        const float* gamma = (const float*)d_in[base + 5];
        const float* beta  = (const float*)d_in[base + 6];
        const int K = Ks[L], Mid = Mids[L], Mout = Mouts[L];

        // aggregation (with fused BN-apply+ReLU of previous layer for L>0)
        if (L == 0) {
            k_agg16<128, false><<<(n + 15) / 16, 256, 0, stream>>>(
                h0, rowp, deg, ss, eps, nullptr, nullptr, P1, n);
        } else {
            // previous layer's Mout == 256 for L=1,2
            k_agg16<256, true><<<(n + 7) / 8, 256, 0, stream>>>(
                P0, rowp, deg, ss, eps, stats + 2 * 256, stats + 3 * 256, P1, n);
        }

        // GEMM1 (+ReLU)
        if (Mid == 256) k_gemmf<256, true, false><<<gx, 512, 0, stream>>>(P1, wh[2*L+0], b1, P2, nullptr, n, K);
        else            k_gemmf<128, true, false><<<gx, 512, 0, stream>>>(P1, wh[2*L+0], b1, P2, nullptr, n, K);

        // GEMM2 (+fused BN stats)
        hipMemsetAsync(stats, 0, 2 * (size_t)Mout * sizeof(float), stream);
        if (Mout == 256) k_gemmf<256, false, true><<<gx, 512, 0, stream>>>(P2, wh[2*L+1], b2, P0, stats, n, Mid);
        else             k_gemmf<128, false, true><<<gx, 512, 0, stream>>>(P2, wh[2*L+1], b2, P0, stats, n, Mid);

        k_bnprep<<<1, Mout, 0, stream>>>(stats, gamma, beta, n, Mout);
    }

    // ---- readout (applies layer-2 BN affine, no relu) ----
    hipMemsetAsync(gsum, 0, NG * 128 * sizeof(float), stream);
    hipMemsetAsync(gcnt, 0, NG * sizeof(int), stream);
    k_readout_bn<<<256, 256, 0, stream>>>(P0, stats, gid, gsum, gcnt, n);
    k_final<<<4, 256, 0, stream>>>(gsum, gcnt, (float*)d_out);
}

// Round 4
// 540.142 us; speedup vs baseline: 1.6748x; 1.6748x over previous
//
#include <hip/hip_runtime.h>

#define NG 8   // graphs

typedef _Float16 half8 __attribute__((ext_vector_type(8)));
typedef float    f32x4 __attribute__((ext_vector_type(4)));

// ---------------- casts ----------------

__global__ __launch_bounds__(256)
void k_cast16(const float* __restrict__ in, _Float16* __restrict__ out, int n8) {
    int i = blockIdx.x * 256 + threadIdx.x;
    if (i < n8) {
        const float4 a = *(const float4*)(in + (size_t)i * 8);
        const float4 b = *(const float4*)(in + (size_t)i * 8 + 4);
        half8 o;
        o[0] = (_Float16)a.x; o[1] = (_Float16)a.y; o[2] = (_Float16)a.z; o[3] = (_Float16)a.w;
        o[4] = (_Float16)b.x; o[5] = (_Float16)b.y; o[6] = (_Float16)b.z; o[7] = (_Float16)b.w;
        *(half8*)(out + (size_t)i * 8) = o;
    }
}

// ---------------- CSR build ----------------

__global__ __launch_bounds__(256)
void k_deg(const int* __restrict__ dst, int* __restrict__ deg, int E) {
    int i = blockIdx.x * 256 + threadIdx.x;
    if (i < E) atomicAdd(&deg[dst[i]], 1);
}

__global__ __launch_bounds__(1024)
void k_scan_a(const int* __restrict__ deg, int* __restrict__ incl,
              int* __restrict__ bsum, int n) {
    __shared__ int s[1024];
    int t = threadIdx.x;
    int base = blockIdx.x * 1024;
    int v = (base + t < n) ? deg[base + t] : 0;
    s[t] = v;
    __syncthreads();
    for (int off = 1; off < 1024; off <<= 1) {
        int x = 0;
        if (t >= off) x = s[t - off];
        __syncthreads();
        if (t >= off) s[t] += x;
        __syncthreads();
    }
    if (base + t < n) incl[base + t] = s[t];
    if (t == 1023) bsum[blockIdx.x] = s[1023];
}

__global__ void k_scan_b(int* bsum, int nb) {
    if (threadIdx.x == 0 && blockIdx.x == 0) {
        int run = 0;
        for (int i = 0; i < nb; ++i) { int v = bsum[i]; bsum[i] = run; run += v; }
    }
}

__global__ __launch_bounds__(256)
void k_scan_c(const int* __restrict__ incl, const int* __restrict__ deg,
              const int* __restrict__ bsum, int* __restrict__ rowp, int n) {
    int i = blockIdx.x * 256 + threadIdx.x;
    if (i < n) rowp[i] = incl[i] - deg[i] + bsum[i >> 10];
}

__global__ __launch_bounds__(256)
void k_scatter(const int* __restrict__ src, const int* __restrict__ dst,
               const int* __restrict__ rowp, int* __restrict__ cur,
               int* __restrict__ ss, int E) {
    int i = blockIdx.x * 256 + threadIdx.x;
    if (i < E) {
        int d = dst[i];
        int pos = rowp[d] + atomicAdd(&cur[d], 1);
        ss[pos] = src[i];
    }
}

// ---------------- aggregation (fp16 rows, fp32 accum), fused BN-apply+ReLU ----------------

template<int K, bool AFFINE>
__global__ __launch_bounds__(256)
void k_agg16(const _Float16* __restrict__ h, const int* __restrict__ rowp,
             const int* __restrict__ deg, const int* __restrict__ ss,
             const float* __restrict__ eps, const float* __restrict__ scp,
             const float* __restrict__ shp, _Float16* __restrict__ z, int n) {
    constexpr int TPN = K / 8;
    constexpr int NPB = 256 / TPN;
    int node = blockIdx.x * NPB + threadIdx.x / TPN;
    int lane = threadIdx.x % TPN;
    if (node >= n) return;
    float e1 = 1.0f + eps[0];
    const int c0 = lane * 8;
    float sc[8], sh[8];
    if (AFFINE) {
#pragma unroll
        for (int e = 0; e < 8; ++e) { sc[e] = scp[c0 + e]; sh[e] = shp[c0 + e]; }
    }
    size_t base = (size_t)node * K + c0;
    half8 v = *(const half8*)(h + base);
    float a[8];
#pragma unroll
    for (int e = 0; e < 8; ++e) {
        float f = (float)v[e];
        if (AFFINE) f = fmaxf(f * sc[e] + sh[e], 0.0f);
        a[e] = f * e1;
    }
    int s  = rowp[node];
    int dn = deg[node];
    int j = 0;
    for (; j + 2 <= dn; j += 2) {
        int u0 = ss[s + j], u1 = ss[s + j + 1];
        half8 h0 = *(const half8*)(h + (size_t)u0 * K + c0);
        half8 h1 = *(const half8*)(h + (size_t)u1 * K + c0);
#pragma unroll
        for (int e = 0; e < 8; ++e) {
            float f0 = (float)h0[e], f1 = (float)h1[e];
            if (AFFINE) {
                f0 = fmaxf(f0 * sc[e] + sh[e], 0.0f);
                f1 = fmaxf(f1 * sc[e] + sh[e], 0.0f);
            }
            a[e] += f0 + f1;
        }
    }
    if (j < dn) {
        int u = ss[s + j];
        half8 hv = *(const half8*)(h + (size_t)u * K + c0);
#pragma unroll
        for (int e = 0; e < 8; ++e) {
            float f = (float)hv[e];
            if (AFFINE) f = fmaxf(f * sc[e] + sh[e], 0.0f);
            a[e] += f;
        }
    }
    half8 o;
#pragma unroll
    for (int e = 0; e < 8; ++e) o[e] = (_Float16)a[e];
    *(half8*)(z + base) = o;
}

// ---------------- MFMA GEMM: C = (relu)(A @ W^T + bias), full-M tile ----------------
// BM=64, BN=M, BK=64. 512 threads (8 waves: 2 row x 4 col). No global atomics.

template<int M, bool RELU>
__global__ __launch_bounds__(512)
void k_gemmf(const _Float16* __restrict__ A, const _Float16* __restrict__ W,
             const float* __restrict__ bias, _Float16* __restrict__ C,
             int n, int K) {
    constexpr int FN   = M / 64;     // n-frags per wave (4 or 2)
    constexpr int BISS = M / 64;     // B staging issues (64 rows each)
    __shared__ char smem[8192 + M * 128];
    char* As = smem;
    char* Bs = smem + 8192;
    const int tid  = threadIdx.x;
    const int lane = tid & 63;
    const int wid  = tid >> 6;       // 0..7
    const int wr   = wid >> 2;       // 0..1  (32 rows each)
    const int wc   = wid & 3;        // 0..3
    const int brow = blockIdx.x * 64;
    const int srow = tid >> 3;       // 0..63
    const int spk  = (tid & 7) << 4; // phys kbyte 0..112

    f32x4 acc[2][FN];
#pragma unroll
    for (int m = 0; m < 2; ++m)
#pragma unroll
        for (int nn = 0; nn < FN; ++nn) acc[m][nn] = (f32x4){0.f, 0.f, 0.f, 0.f};

    uint4 ar, br[BISS];
    const int nk = K >> 6;
    const int lkA = spk ^ ((srow & 7) << 4);

    // prefetch t=0
    {
        int ga = brow + srow; if (ga > n - 1) ga = n - 1;
        ar = *(const uint4*)((const char*)A + ((size_t)ga * K) * 2 + lkA);
#pragma unroll
        for (int i = 0; i < BISS; ++i)
            br[i] = *(const uint4*)((const char*)W + ((size_t)(i * 64 + srow) * K) * 2 + lkA);
    }

    for (int t = 0; t < nk; ++t) {
        __syncthreads();
        *(uint4*)(As + srow * 128 + spk) = ar;
#pragma unroll
        for (int i = 0; i < BISS; ++i)
            *(uint4*)(Bs + (i * 64 + srow) * 128 + spk) = br[i];
        __syncthreads();
        if (t + 1 < nk) {
            int k0 = (t + 1) << 6;
            int ga = brow + srow; if (ga > n - 1) ga = n - 1;
            ar = *(const uint4*)((const char*)A + ((size_t)ga * K + k0) * 2 + lkA);
#pragma unroll
            for (int i = 0; i < BISS; ++i)
                br[i] = *(const uint4*)((const char*)W + ((size_t)(i * 64 + srow) * K + k0) * 2 + lkA);
        }
#pragma unroll
        for (int kk = 0; kk < 2; ++kk) {
            const int kb = kk * 64 + (lane >> 4) * 16;
            half8 af[2], bf[FN];
#pragma unroll
            for (int m = 0; m < 2; ++m) {
                int rowA = wr * 32 + m * 16 + (lane & 15);
                af[m] = *(const half8*)(As + rowA * 128 + (kb ^ ((rowA & 7) << 4)));
            }
#pragma unroll
            for (int nn = 0; nn < FN; ++nn) {
                int rowB = wc * (FN * 16) + nn * 16 + (lane & 15);
                bf[nn] = *(const half8*)(Bs + rowB * 128 + (kb ^ ((rowB & 7) << 4)));
            }
#pragma unroll
            for (int m = 0; m < 2; ++m)
#pragma unroll
                for (int nn = 0; nn < FN; ++nn)
                    acc[m][nn] = __builtin_amdgcn_mfma_f32_16x16x32_f16(af[m], bf[nn], acc[m][nn], 0, 0, 0);
        }
    }

    __syncthreads();   // done reading As/Bs; repurpose smem as per-wave transpose buf
    char* tb = smem + wid * 2304;           // [16][72] fp16, 144 B row stride
    const int colbase = wc * (FN * 16);
    float bb[FN];
#pragma unroll
    for (int nn = 0; nn < FN; ++nn) bb[nn] = bias[colbase + nn * 16 + (lane & 15)];
    constexpr int GRP = FN * 2;             // 8-col groups per wave tile
    constexpr int RPI = 64 / GRP;           // rows per read iter
    constexpr int NIT = 16 / RPI;           // read iters per m-chunk
    const int g    = lane & (GRP - 1);
    const int rl   = lane / GRP;
    const int rcol = colbase + g * 8;
    const int rowbase = brow + wr * 32;
#pragma unroll
    for (int m = 0; m < 2; ++m) {
#pragma unroll
        for (int nn = 0; nn < FN; ++nn)
#pragma unroll
            for (int j = 0; j < 4; ++j) {
                float v = acc[m][nn][j] + bb[nn];
                if (RELU) v = fmaxf(v, 0.0f);
                *(_Float16*)(tb + ((lane >> 4) * 4 + j) * 144 + (nn * 16 + (lane & 15)) * 2) = (_Float16)v;
            }
#pragma unroll
        for (int it = 0; it < NIT; ++it) {
            int lr = it * RPI + rl;
            int grow = rowbase + m * 16 + lr;
            half8 v = *(const half8*)(tb + lr * 144 + g * 16);
            if (grow < n) *(half8*)(C + (size_t)grow * M + rcol) = v;
        }
    }
}

// ---------------- BN stats: atomic-free (per-block partials) ----------------
// 256 blocks x 256 threads; partial[b][2M]: s at [b][c], s2 at [b][M+c].

template<int M>
__global__ __launch_bounds__(256)
void k_bnstats(const _Float16* __restrict__ z, float* __restrict__ partial, int n) {
    constexpr int CG = M / 8;        // col groups (32 or 16)
    constexpr int RL = 256 / CG;     // row lanes (8 or 16)
    __shared__ float red[256][16];
    const int t  = threadIdx.x;
    const int cg = t % CG;
    const int rl = t / CG;
    const int c0 = cg * 8;
    float s[8], q[8];
#pragma unroll
    for (int e = 0; e < 8; ++e) { s[e] = 0.f; q[e] = 0.f; }
    for (int r = blockIdx.x * RL + rl; r < n; r += 256 * RL) {
        half8 v = *(const half8*)(z + (size_t)r * M + c0);
#pragma unroll
        for (int e = 0; e < 8; ++e) { float f = (float)v[e]; s[e] += f; q[e] += f * f; }
    }
#pragma unroll
    for (int e = 0; e < 8; ++e) { red[t][e] = s[e]; red[t][8 + e] = q[e]; }
    __syncthreads();
    for (int off = 128; off >= CG; off >>= 1) {
        if (t < off) {
#pragma unroll
            for (int e = 0; e < 16; ++e) red[t][e] += red[t + off][e];
        }
        __syncthreads();
    }
    if (t < CG) {
        float* p = partial + (size_t)blockIdx.x * 2 * M;
#pragma unroll
        for (int e = 0; e < 8; ++e) {
            p[t * 8 + e]     = red[t][e];
            p[M + t * 8 + e] = red[t][8 + e];
        }
    }
}

// reduce partials + compute scale/shift. grid = M/4 blocks x 256 thr (1 wave per col).
template<int M>
__global__ __launch_bounds__(256)
void k_bnred(const float* __restrict__ partial, const float* __restrict__ gamma,
             const float* __restrict__ beta, float* __restrict__ scale,
             float* __restrict__ shift, int n) {
    const int w = threadIdx.x >> 6, lane = threadIdx.x & 63;
    const int c = blockIdx.x * 4 + w;
    float s = 0.f, q = 0.f;
#pragma unroll
    for (int it = 0; it < 4; ++it) {
        int b = it * 64 + lane;
        s += partial[(size_t)b * 2 * M + c];
        q += partial[(size_t)b * 2 * M + M + c];
    }
#pragma unroll
    for (int mk = 1; mk < 64; mk <<= 1) {
        s += __shfl_xor(s, mk, 64);
        q += __shfl_xor(q, mk, 64);
    }
    if (lane == 0) {
        float invN = 1.0f / (float)n;
        float mean = s * invN;
        float var  = q * invN - mean * mean;
        float sc   = rsqrtf(var + 1e-5f) * gamma[c];
        scale[c] = sc;
        shift[c] = beta[c] - mean * sc;
    }
}

// ---------------- graph readout (fused final BN affine) ----------------

__global__ __launch_bounds__(256)
void k_readout_bn(const _Float16* __restrict__ z, const float* __restrict__ scale,
                  const float* __restrict__ shift, const int* __restrict__ gid,
                  float* __restrict__ gsum, int* __restrict__ gcnt, int n) {
    __shared__ float ls[NG * 128];
    __shared__ int   lc[NG];
    for (int i = threadIdx.x; i < NG * 128; i += 256) ls[i] = 0.0f;
    if (threadIdx.x < NG) lc[threadIdx.x] = 0;
    __syncthreads();
    int c  = threadIdx.x & 127;
    int ro = threadIdx.x >> 7;
    const float sc = scale[c];
    const float sh = shift[c];
    for (int r = blockIdx.x * 2 + ro; r < n; r += gridDim.x * 2) {
        int g = gid[r];
        float v = (float)z[(size_t)r * 128 + c] * sc + sh;
        atomicAdd(&ls[g * 128 + c], v);
        if (c == 0) atomicAdd(&lc[g], 1);
    }
    __syncthreads();
    for (int i = threadIdx.x; i < NG * 128; i += 256) atomicAdd(&gsum[i], ls[i]);
    if (threadIdx.x < NG) atomicAdd(&gcnt[threadIdx.x], lc[threadIdx.x]);
}

__global__ void k_final(const float* __restrict__ gsum, const int* __restrict__ gcnt,
                        float* __restrict__ out) {
    int i = blockIdx.x * 256 + threadIdx.x;
    if (i < NG * 128) {
        int g = i >> 7;
        out[i] = gsum[i] / fmaxf((float)gcnt[g], 1.0f);
    }
}

// ---------------- host ----------------

extern "C" void kernel_launch(void* const* d_in, const int* in_sizes, int n_in,
                              void* d_out, int out_size, void* d_ws, size_t ws_size,
                              hipStream_t stream) {
    const float* x   = (const float*)d_in[0];
    const int*   src = (const int*)d_in[1];
    const int*   dst = (const int*)d_in[2];
    const int*   gid = (const int*)d_in[3];
    const int n = in_sizes[0] / 128;
    const int E = in_sizes[1];

    auto align = [](size_t o) { return (o + 255) & ~(size_t)255; };
    char* ws = (char*)d_ws;
    size_t off = 0;
    const size_t SZ_H = align((size_t)n * 256 * sizeof(_Float16));
    const size_t SZ_I = align((size_t)n * sizeof(int));

    _Float16* h0 = (_Float16*)(ws + off); off += align((size_t)n * 128 * sizeof(_Float16));
    _Float16* P0 = (_Float16*)(ws + off); off += SZ_H;
    _Float16* P1 = (_Float16*)(ws + off); off += SZ_H;
    _Float16* P2 = (_Float16*)(ws + off); off += SZ_H;
    int*   deg  = (int*)(ws + off);   off += SZ_I;
    int*   incl = (int*)(ws + off);   off += SZ_I;
    int*   rowp = (int*)(ws + off);   off += SZ_I;
    int*   cur  = (int*)(ws + off);   off += SZ_I;
    int*   bsum = (int*)(ws + off);   off += 256 * sizeof(int);
    int*   ss   = (int*)(ws + off);   off += align((size_t)E * sizeof(int));
    float* partial = (float*)(ws + off); off += align(256 * 2 * 256 * sizeof(float));
    float* scale   = (float*)(ws + off); off += align(256 * sizeof(float));
    float* shiftb  = (float*)(ws + off); off += align(256 * sizeof(float));
    float* gsum = (float*)(ws + off); off += align(NG * 128 * sizeof(float));
    int*   gcnt = (int*)(ws + off);   off += align(NG * sizeof(int));
    _Float16* wh[6];
    for (int i = 0; i < 6; ++i) { wh[i] = (_Float16*)(ws + off); off += align(65536 * sizeof(_Float16)); }

    const int Ks[3]    = {128, 256, 256};
    const int Mids[3]  = {256, 256, 128};
    const int Mouts[3] = {256, 256, 128};

    // ---- casts ----
    k_cast16<<<(n * 128 / 8 + 255) / 256, 256, 0, stream>>>(x, h0, n * 128 / 8);
    for (int L = 0; L < 3; ++L) {
        const int base = 4 + 7 * L;
        int n1 = Mids[L] * Ks[L];
        int n2 = Mouts[L] * Mids[L];
        k_cast16<<<(n1 / 8 + 255) / 256, 256, 0, stream>>>((const float*)d_in[base + 0], wh[2 * L + 0], n1 / 8);
        k_cast16<<<(n2 / 8 + 255) / 256, 256, 0, stream>>>((const float*)d_in[base + 2], wh[2 * L + 1], n2 / 8);
    }

    // ---- CSR build (dst-keyed) ----
    hipMemsetAsync(deg, 0, (size_t)n * sizeof(int), stream);
    k_deg<<<(E + 255) / 256, 256, 0, stream>>>(dst, deg, E);
    int nb = (n + 1023) / 1024;
    k_scan_a<<<nb, 1024, 0, stream>>>(deg, incl, bsum, n);
    k_scan_b<<<1, 1, 0, stream>>>(bsum, nb);
    k_scan_c<<<(n + 255) / 256, 256, 0, stream>>>(incl, deg, bsum, rowp, n);
    hipMemsetAsync(cur, 0, (size_t)n * sizeof(int), stream);
    k_scatter<<<(E + 255) / 256, 256, 0, stream>>>(src, dst, rowp, cur, ss, E);

    // ---- layers ----
    const int gx = (n + 63) / 64;
    for (int L = 0; L < 3; ++L) {
        const int base = 4 + 7 * L;
        const float* b1    = (const float*)d_in[base + 1];
        const float* b2    = (const float*)d_in[base + 3];
        const float* eps   = (const float*)d_in[base + 4];
        const float* gamma = (const float*)d_in[base + 5];
        const float* beta  = (const float*)d_in[base + 6];
        const int K = Ks[L], Mid = Mids[L], Mout = Mouts[L];

        if (L == 0) {
            k_agg16<128, false><<<(n + 15) / 16, 256, 0, stream>>>(
                h0, rowp, deg, ss, eps, nullptr, nullptr, P1, n);
        } else {
            k_agg16<256, true><<<(n + 7) / 8, 256, 0, stream>>>(
                P0, rowp, deg, ss, eps, scale, shiftb, P1, n);
        }

        if (Mid == 256) k_gemmf<256, true><<<gx, 512, 0, stream>>>(P1, wh[2*L+0], b1, P2, n, K);
        else            k_gemmf<128, true><<<gx, 512, 0, stream>>>(P1, wh[2*L+0], b1, P2, n, K);

        if (Mout == 256) {
            k_gemmf<256, false><<<gx, 512, 0, stream>>>(P2, wh[2*L+1], b2, P0, n, Mid);
            k_bnstats<256><<<256, 256, 0, stream>>>(P0, partial, n);
            k_bnred<256><<<64, 256, 0, stream>>>(partial, gamma, beta, scale, shiftb, n);
        } else {
            k_gemmf<128, false><<<gx, 512, 0, stream>>>(P2, wh[2*L+1], b2, P0, n, Mid);
            k_bnstats<128><<<256, 256, 0, stream>>>(P0, partial, n);
            k_bnred<128><<<32, 256, 0, stream>>>(partial, gamma, beta, scale, shiftb, n);
        }
    }

    // ---- readout (applies layer-2 BN affine) ----
    hipMemsetAsync(gsum, 0, NG * 128 * sizeof(float), stream);
    hipMemsetAsync(gcnt, 0, NG * sizeof(int), stream);
    k_readout_bn<<<256, 256, 0, stream>>>(P0, scale, shiftb, gid, gsum, gcnt, n);
    k_final<<<4, 256, 0, stream>>>(gsum, gcnt, (float*)d_out);
}

// Round 5
// 524.443 us; speedup vs baseline: 1.7250x; 1.0299x over previous
//
#include <hip/hip_runtime.h>

#define NG 8   // graphs

typedef _Float16 half8 __attribute__((ext_vector_type(8)));
typedef float    f32x4 __attribute__((ext_vector_type(4)));

// ---------------- casts ----------------

__global__ __launch_bounds__(256)
void k_cast16(const float* __restrict__ in, _Float16* __restrict__ out, int n8) {
    int i = blockIdx.x * 256 + threadIdx.x;
    if (i < n8) {
        const float4 a = *(const float4*)(in + (size_t)i * 8);
        const float4 b = *(const float4*)(in + (size_t)i * 8 + 4);
        half8 o;
        o[0] = (_Float16)a.x; o[1] = (_Float16)a.y; o[2] = (_Float16)a.z; o[3] = (_Float16)a.w;
        o[4] = (_Float16)b.x; o[5] = (_Float16)b.y; o[6] = (_Float16)b.z; o[7] = (_Float16)b.w;
        *(half8*)(out + (size_t)i * 8) = o;
    }
}

// ---------------- CSR build ----------------

__global__ __launch_bounds__(256)
void k_deg(const int* __restrict__ dst, int* __restrict__ deg, int E) {
    int i = blockIdx.x * 256 + threadIdx.x;
    if (i < E) atomicAdd(&deg[dst[i]], 1);
}

__global__ __launch_bounds__(1024)
void k_scan_a(const int* __restrict__ deg, int* __restrict__ incl,
              int* __restrict__ bsum, int n) {
    __shared__ int s[1024];
    int t = threadIdx.x;
    int base = blockIdx.x * 1024;
    int v = (base + t < n) ? deg[base + t] : 0;
    s[t] = v;
    __syncthreads();
    for (int off = 1; off < 1024; off <<= 1) {
        int x = 0;
        if (t >= off) x = s[t - off];
        __syncthreads();
        if (t >= off) s[t] += x;
        __syncthreads();
    }
    if (base + t < n) incl[base + t] = s[t];
    if (t == 1023) bsum[blockIdx.x] = s[1023];
}

__global__ void k_scan_b(int* bsum, int nb) {
    if (threadIdx.x == 0 && blockIdx.x == 0) {
        int run = 0;
        for (int i = 0; i < nb; ++i) { int v = bsum[i]; bsum[i] = run; run += v; }
    }
}

__global__ __launch_bounds__(256)
void k_scan_c(const int* __restrict__ incl, const int* __restrict__ deg,
              const int* __restrict__ bsum, int* __restrict__ rowp, int n) {
    int i = blockIdx.x * 256 + threadIdx.x;
    if (i < n) rowp[i] = incl[i] - deg[i] + bsum[i >> 10];
}

__global__ __launch_bounds__(256)
void k_scatter(const int* __restrict__ src, const int* __restrict__ dst,
               const int* __restrict__ rowp, int* __restrict__ cur,
               int* __restrict__ ss, int E) {
    int i = blockIdx.x * 256 + threadIdx.x;
    if (i < E) {
        int d = dst[i];
        int pos = rowp[d] + atomicAdd(&cur[d], 1);
        ss[pos] = src[i];
    }
}

// ---------------- aggregation (fp16 rows, fp32 accum), fused BN-apply+ReLU ----------------

template<int K, bool AFFINE>
__global__ __launch_bounds__(256)
void k_agg16(const _Float16* __restrict__ h, const int* __restrict__ rowp,
             const int* __restrict__ deg, const int* __restrict__ ss,
             const float* __restrict__ eps, const float* __restrict__ scp,
             const float* __restrict__ shp, _Float16* __restrict__ z, int n) {
    constexpr int TPN = K / 8;
    constexpr int NPB = 256 / TPN;
    int node = blockIdx.x * NPB + threadIdx.x / TPN;
    int lane = threadIdx.x % TPN;
    if (node >= n) return;
    float e1 = 1.0f + eps[0];
    const int c0 = lane * 8;
    float sc[8], sh[8];
    if (AFFINE) {
#pragma unroll
        for (int e = 0; e < 8; ++e) { sc[e] = scp[c0 + e]; sh[e] = shp[c0 + e]; }
    }
    size_t base = (size_t)node * K + c0;
    half8 v = *(const half8*)(h + base);
    float a[8];
#pragma unroll
    for (int e = 0; e < 8; ++e) {
        float f = (float)v[e];
        if (AFFINE) f = fmaxf(f * sc[e] + sh[e], 0.0f);
        a[e] = f * e1;
    }
    int s  = rowp[node];
    int dn = deg[node];
    int j = 0;
    for (; j + 4 <= dn; j += 4) {
        int u0 = ss[s + j], u1 = ss[s + j + 1], u2 = ss[s + j + 2], u3 = ss[s + j + 3];
        half8 h0 = *(const half8*)(h + (size_t)u0 * K + c0);
        half8 h1 = *(const half8*)(h + (size_t)u1 * K + c0);
        half8 h2 = *(const half8*)(h + (size_t)u2 * K + c0);
        half8 h3 = *(const half8*)(h + (size_t)u3 * K + c0);
#pragma unroll
        for (int e = 0; e < 8; ++e) {
            float f0 = (float)h0[e], f1 = (float)h1[e];
            float f2 = (float)h2[e], f3 = (float)h3[e];
            if (AFFINE) {
                f0 = fmaxf(f0 * sc[e] + sh[e], 0.0f);
                f1 = fmaxf(f1 * sc[e] + sh[e], 0.0f);
                f2 = fmaxf(f2 * sc[e] + sh[e], 0.0f);
                f3 = fmaxf(f3 * sc[e] + sh[e], 0.0f);
            }
            a[e] += (f0 + f1) + (f2 + f3);
        }
    }
    for (; j < dn; ++j) {
        int u = ss[s + j];
        half8 hv = *(const half8*)(h + (size_t)u * K + c0);
#pragma unroll
        for (int e = 0; e < 8; ++e) {
            float f = (float)hv[e];
            if (AFFINE) f = fmaxf(f * sc[e] + sh[e], 0.0f);
            a[e] += f;
        }
    }
    half8 o;
#pragma unroll
    for (int e = 0; e < 8; ++e) o[e] = (_Float16)a[e];
    *(half8*)(z + base) = o;
}

// ---------------- fused MLP: C = (A@W1^T+b1).relu() @ W2^T + b2, + BN partials ----------------
// A: [n x K] fp16; W1: [MID x K] fp16; W2: [MOUT x MID] fp16.
// One block = 64 rows, 512 threads (8 waves, 2 row-halves x 4 col-quarters).
// Y (64 x MID) lives in LDS between the two GEMMs. No global atomics:
// per-(block, row-half) BN partials at partial[(bid*2+wr)*2*MOUT + {c, MOUT+c}].

template<int K, int MID, int MOUT>
__global__ __launch_bounds__(512)
void k_mlp(const _Float16* __restrict__ A, const _Float16* __restrict__ W1,
           const float* __restrict__ b1, const _Float16* __restrict__ W2,
           const float* __restrict__ b2, _Float16* __restrict__ C,
           float* __restrict__ partial, int n) {
    constexpr int FN1 = MID / 64, WC1 = 16 * FN1;
    constexpr int FN2 = MOUT / 64, WC2 = 16 * FN2;
    constexpr int BI1 = MID / 64;    // W1 staging issues per k-step
    constexpr int BI2 = MOUT / 64;   // W2 staging issues per k-step
    __shared__ char smem[8192 + 32768 + MID * 128];
    char* As = smem;                 // [64][128B]
    char* Ws = smem + 8192;          // [max rows][128B] (W1, then W2)
    char* Ys = smem + 8192 + 32768;  // [64][MID*2 B], XOR-swizzled
    const int tid  = threadIdx.x;
    const int lane = tid & 63;
    const int wid  = tid >> 6;
    const int wr   = wid >> 2;       // 0..1
    const int wc   = wid & 3;        // 0..3
    const int brow = blockIdx.x * 64;
    const int srow = tid >> 3;       // 0..63
    const int spk  = (tid & 7) << 4; // 0..112
    const int lkA  = spk ^ ((srow & 7) << 4);

    // ================= phase 1: Y = relu(A @ W1^T + b1) =================
    f32x4 acc1[2][FN1];
#pragma unroll
    for (int m = 0; m < 2; ++m)
#pragma unroll
        for (int nn = 0; nn < FN1; ++nn) acc1[m][nn] = (f32x4){0.f, 0.f, 0.f, 0.f};

    uint4 ar, wr1[BI1];
    const int nk1 = K >> 6;
    {
        int ga = brow + srow; if (ga > n - 1) ga = n - 1;
        ar = *(const uint4*)((const char*)A + ((size_t)ga * K) * 2 + lkA);
#pragma unroll
        for (int i = 0; i < BI1; ++i)
            wr1[i] = *(const uint4*)((const char*)W1 + ((size_t)(i * 64 + srow) * K) * 2 + lkA);
    }
    for (int t = 0; t < nk1; ++t) {
        __syncthreads();
        *(uint4*)(As + srow * 128 + spk) = ar;
#pragma unroll
        for (int i = 0; i < BI1; ++i)
            *(uint4*)(Ws + (i * 64 + srow) * 128 + spk) = wr1[i];
        __syncthreads();
        if (t + 1 < nk1) {
            int k0 = (t + 1) << 6;
            int ga = brow + srow; if (ga > n - 1) ga = n - 1;
            ar = *(const uint4*)((const char*)A + ((size_t)ga * K + k0) * 2 + lkA);
#pragma unroll
            for (int i = 0; i < BI1; ++i)
                wr1[i] = *(const uint4*)((const char*)W1 + ((size_t)(i * 64 + srow) * K + k0) * 2 + lkA);
        }
#pragma unroll
        for (int kk = 0; kk < 2; ++kk) {
            const int kb = kk * 64 + (lane >> 4) * 16;
            half8 af[2], bf[FN1];
#pragma unroll
            for (int m = 0; m < 2; ++m) {
                int rowA = wr * 32 + m * 16 + (lane & 15);
                af[m] = *(const half8*)(As + rowA * 128 + (kb ^ ((rowA & 7) << 4)));
            }
#pragma unroll
            for (int nn = 0; nn < FN1; ++nn) {
                int rowB = wc * WC1 + nn * 16 + (lane & 15);
                bf[nn] = *(const half8*)(Ws + rowB * 128 + (kb ^ ((rowB & 7) << 4)));
            }
#pragma unroll
            for (int m = 0; m < 2; ++m)
#pragma unroll
                for (int nn = 0; nn < FN1; ++nn)
                    acc1[m][nn] = __builtin_amdgcn_mfma_f32_16x16x32_f16(af[m], bf[nn], acc1[m][nn], 0, 0, 0);
        }
    }

    // bias + relu -> Ys (fp16, swizzled)
    {
        float bb1[FN1];
#pragma unroll
        for (int nn = 0; nn < FN1; ++nn) bb1[nn] = b1[wc * WC1 + nn * 16 + (lane & 15)];
#pragma unroll
        for (int m = 0; m < 2; ++m)
#pragma unroll
            for (int nn = 0; nn < FN1; ++nn)
#pragma unroll
                for (int j = 0; j < 4; ++j) {
                    int row = wr * 32 + m * 16 + (lane >> 4) * 4 + j;
                    int col = wc * WC1 + nn * 16 + (lane & 15);
                    float v = fmaxf(acc1[m][nn][j] + bb1[nn], 0.0f);
                    *(_Float16*)(Ys + row * (MID * 2) + ((col * 2) ^ ((row & 7) << 4))) = (_Float16)v;
                }
    }

    // ================= phase 2: C = Y @ W2^T + b2 =================
    f32x4 acc2[2][FN2];
#pragma unroll
    for (int m = 0; m < 2; ++m)
#pragma unroll
        for (int nn = 0; nn < FN2; ++nn) acc2[m][nn] = (f32x4){0.f, 0.f, 0.f, 0.f};

    uint4 wr2[BI2];
#pragma unroll
    for (int i = 0; i < BI2; ++i)
        wr2[i] = *(const uint4*)((const char*)W2 + ((size_t)(i * 64 + srow) * MID) * 2 + lkA);

    const int nk2 = MID >> 6;
    for (int t = 0; t < nk2; ++t) {
        __syncthreads();   // t=0: Y visible + W1 reads done; t>0: prior W2 reads done
#pragma unroll
        for (int i = 0; i < BI2; ++i)
            *(uint4*)(Ws + (i * 64 + srow) * 128 + spk) = wr2[i];
        __syncthreads();
        if (t + 1 < nk2) {
            int k0 = (t + 1) << 6;
#pragma unroll
            for (int i = 0; i < BI2; ++i)
                wr2[i] = *(const uint4*)((const char*)W2 + ((size_t)(i * 64 + srow) * MID + k0) * 2 + lkA);
        }
#pragma unroll
        for (int kk = 0; kk < 2; ++kk) {
            const int kb = kk * 64 + (lane >> 4) * 16;
            half8 af[2], bf[FN2];
#pragma unroll
            for (int m = 0; m < 2; ++m) {
                int rowA = wr * 32 + m * 16 + (lane & 15);
                af[m] = *(const half8*)(Ys + rowA * (MID * 2) + ((t * 128 + kb) ^ ((rowA & 7) << 4)));
            }
#pragma unroll
            for (int nn = 0; nn < FN2; ++nn) {
                int rowB = wc * WC2 + nn * 16 + (lane & 15);
                bf[nn] = *(const half8*)(Ws + rowB * 128 + (kb ^ ((rowB & 7) << 4)));
            }
#pragma unroll
            for (int m = 0; m < 2; ++m)
#pragma unroll
                for (int nn = 0; nn < FN2; ++nn)
                    acc2[m][nn] = __builtin_amdgcn_mfma_f32_16x16x32_f16(af[m], bf[nn], acc2[m][nn], 0, 0, 0);
        }
    }

    // ================= epilogue: coalesced store + BN partials =================
    __syncthreads();   // Ws/As reads done; reuse smem as transpose buffers
    char* tb = smem + wid * 2304;   // per-wave [16][72] fp16 (144 B row stride)
    const int colbase = wc * WC2;
    float bb2[FN2];
#pragma unroll
    for (int nn = 0; nn < FN2; ++nn) bb2[nn] = b2[colbase + nn * 16 + (lane & 15)];
    constexpr int GRP = FN2 * 2;
    constexpr int RPI = 64 / GRP;
    constexpr int NIT = 16 / RPI;
    const int g    = lane & (GRP - 1);
    const int rl   = lane / GRP;
    const int rcol = colbase + g * 8;
    const int rowbase = brow + wr * 32;
    float s[8], q[8];
#pragma unroll
    for (int e = 0; e < 8; ++e) { s[e] = 0.f; q[e] = 0.f; }
#pragma unroll
    for (int m = 0; m < 2; ++m) {
#pragma unroll
        for (int nn = 0; nn < FN2; ++nn)
#pragma unroll
            for (int j = 0; j < 4; ++j) {
                float v = acc2[m][nn][j] + bb2[nn];
                *(_Float16*)(tb + ((lane >> 4) * 4 + j) * 144 + (nn * 16 + (lane & 15)) * 2) = (_Float16)v;
            }
#pragma unroll
        for (int it = 0; it < NIT; ++it) {
            int lr = it * RPI + rl;
            int grow = rowbase + m * 16 + lr;
            half8 v = *(const half8*)(tb + lr * 144 + g * 16);
            if (grow < n) {
                *(half8*)(C + (size_t)grow * MOUT + rcol) = v;
#pragma unroll
                for (int e = 0; e < 8; ++e) { float f = (float)v[e]; s[e] += f; q[e] += f * f; }
            }
        }
    }
#pragma unroll
    for (int e = 0; e < 8; ++e) {
        for (int mk = GRP; mk < 64; mk <<= 1) {
            s[e] += __shfl_xor(s[e], mk, 64);
            q[e] += __shfl_xor(q[e], mk, 64);
        }
    }
    if (lane < GRP) {
        float* p = partial + ((size_t)blockIdx.x * 2 + wr) * 2 * MOUT;
#pragma unroll
        for (int e = 0; e < 8; ++e) {
            p[rcol + e]        = s[e];
            p[MOUT + rcol + e] = q[e];
        }
    }
}

// ---------------- BN reduce: partial rows -> scale/shift ----------------
// grid = M/4 blocks x 256 threads (1 wave per column).

template<int M>
__global__ __launch_bounds__(256)
void k_bnred(const float* __restrict__ partial, const float* __restrict__ gamma,
             const float* __restrict__ beta, float* __restrict__ scale,
             float* __restrict__ shift, int n, int nrows) {
    const int w = threadIdx.x >> 6, lane = threadIdx.x & 63;
    const int c = blockIdx.x * 4 + w;
    float s = 0.f, q = 0.f;
    for (int b = lane; b < nrows; b += 64) {
        s += partial[(size_t)b * 2 * M + c];
        q += partial[(size_t)b * 2 * M + M + c];
    }
#pragma unroll
    for (int mk = 1; mk < 64; mk <<= 1) {
        s += __shfl_xor(s, mk, 64);
        q += __shfl_xor(q, mk, 64);
    }
    if (lane == 0) {
        float invN = 1.0f / (float)n;
        float mean = s * invN;
        float var  = q * invN - mean * mean;
        float sc   = rsqrtf(var + 1e-5f) * gamma[c];
        scale[c] = sc;
        shift[c] = beta[c] - mean * sc;
    }
}

// ---------------- graph readout (fused final BN affine) ----------------

__global__ __launch_bounds__(256)
void k_readout_bn(const _Float16* __restrict__ z, const float* __restrict__ scale,
                  const float* __restrict__ shift, const int* __restrict__ gid,
                  float* __restrict__ gsum, int* __restrict__ gcnt, int n) {
    __shared__ float ls[NG * 128];
    __shared__ int   lc[NG];
    for (int i = threadIdx.x; i < NG * 128; i += 256) ls[i] = 0.0f;
    if (threadIdx.x < NG) lc[threadIdx.x] = 0;
    __syncthreads();
    int c  = threadIdx.x & 127;
    int ro = threadIdx.x >> 7;
    const float sc = scale[c];
    const float sh = shift[c];
    for (int r = blockIdx.x * 2 + ro; r < n; r += gridDim.x * 2) {
        int g = gid[r];
        float v = (float)z[(size_t)r * 128 + c] * sc + sh;
        atomicAdd(&ls[g * 128 + c], v);
        if (c == 0) atomicAdd(&lc[g], 1);
    }
    __syncthreads();
    for (int i = threadIdx.x; i < NG * 128; i += 256) atomicAdd(&gsum[i], ls[i]);
    if (threadIdx.x < NG) atomicAdd(&gcnt[threadIdx.x], lc[threadIdx.x]);
}

__global__ void k_final(const float* __restrict__ gsum, const int* __restrict__ gcnt,
                        float* __restrict__ out) {
    int i = blockIdx.x * 256 + threadIdx.x;
    if (i < NG * 128) {
        int g = i >> 7;
        out[i] = gsum[i] / fmaxf((float)gcnt[g], 1.0f);
    }
}

// ---------------- host ----------------

extern "C" void kernel_launch(void* const* d_in, const int* in_sizes, int n_in,
                              void* d_out, int out_size, void* d_ws, size_t ws_size,
                              hipStream_t stream) {
    const float* x   = (const float*)d_in[0];
    const int*   src = (const int*)d_in[1];
    const int*   dst = (const int*)d_in[2];
    const int*   gid = (const int*)d_in[3];
    const int n = in_sizes[0] / 128;
    const int E = in_sizes[1];

    auto align = [](size_t o) { return (o + 255) & ~(size_t)255; };
    char* ws = (char*)d_ws;
    size_t off = 0;
    const size_t SZ_H = align((size_t)n * 256 * sizeof(_Float16));
    const size_t SZ_I = align((size_t)n * sizeof(int));
    const int gx = (n + 63) / 64;

    _Float16* h0 = (_Float16*)(ws + off); off += align((size_t)n * 128 * sizeof(_Float16));
    _Float16* P0 = (_Float16*)(ws + off); off += SZ_H;
    _Float16* P1 = (_Float16*)(ws + off); off += SZ_H;
    int*   deg  = (int*)(ws + off);   off += SZ_I;
    int*   incl = (int*)(ws + off);   off += SZ_I;
    int*   rowp = (int*)(ws + off);   off += SZ_I;
    int*   cur  = (int*)(ws + off);   off += SZ_I;
    int*   bsum = (int*)(ws + off);   off += 256 * sizeof(int);
    int*   ss   = (int*)(ws + off);   off += align((size_t)E * sizeof(int));
    float* partial = (float*)(ws + off); off += align((size_t)gx * 2 * 2 * 256 * sizeof(float));
    float* scale   = (float*)(ws + off); off += align(256 * sizeof(float));
    float* shiftb  = (float*)(ws + off); off += align(256 * sizeof(float));
    float* gsum = (float*)(ws + off); off += align(NG * 128 * sizeof(float));
    int*   gcnt = (int*)(ws + off);   off += align(NG * sizeof(int));
    _Float16* wh[6];
    for (int i = 0; i < 6; ++i) { wh[i] = (_Float16*)(ws + off); off += align(65536 * sizeof(_Float16)); }

    const int Ks[3]    = {128, 256, 256};
    const int Mids[3]  = {256, 256, 128};
    const int Mouts[3] = {256, 256, 128};

    // ---- casts ----
    k_cast16<<<(n * 128 / 8 + 255) / 256, 256, 0, stream>>>(x, h0, n * 128 / 8);
    for (int L = 0; L < 3; ++L) {
        const int base = 4 + 7 * L;
        int n1 = Mids[L] * Ks[L];
        int n2 = Mouts[L] * Mids[L];
        k_cast16<<<(n1 / 8 + 255) / 256, 256, 0, stream>>>((const float*)d_in[base + 0], wh[2 * L + 0], n1 / 8);
        k_cast16<<<(n2 / 8 + 255) / 256, 256, 0, stream>>>((const float*)d_in[base + 2], wh[2 * L + 1], n2 / 8);
    }

    // ---- CSR build (dst-keyed) ----
    hipMemsetAsync(deg, 0, (size_t)n * sizeof(int), stream);
    k_deg<<<(E + 255) / 256, 256, 0, stream>>>(dst, deg, E);
    int nb = (n + 1023) / 1024;
    k_scan_a<<<nb, 1024, 0, stream>>>(deg, incl, bsum, n);
    k_scan_b<<<1, 1, 0, stream>>>(bsum, nb);
    k_scan_c<<<(n + 255) / 256, 256, 0, stream>>>(incl, deg, bsum, rowp, n);
    hipMemsetAsync(cur, 0, (size_t)n * sizeof(int), stream);
    k_scatter<<<(E + 255) / 256, 256, 0, stream>>>(src, dst, rowp, cur, ss, E);

    // ---- layers ----
    for (int L = 0; L < 3; ++L) {
        const int base = 4 + 7 * L;
        const float* b1    = (const float*)d_in[base + 1];
        const float* b2    = (const float*)d_in[base + 3];
        const float* eps   = (const float*)d_in[base + 4];
        const float* gamma = (const float*)d_in[base + 5];
        const float* beta  = (const float*)d_in[base + 6];
        const int Mout = Mouts[L];

        if (L == 0) {
            k_agg16<128, false><<<(n + 15) / 16, 256, 0, stream>>>(
                h0, rowp, deg, ss, eps, nullptr, nullptr, P1, n);
            k_mlp<128, 256, 256><<<gx, 512, 0, stream>>>(P1, wh[0], b1, wh[1], b2, P0, partial, n);
        } else if (L == 1) {
            k_agg16<256, true><<<(n + 7) / 8, 256, 0, stream>>>(
                P0, rowp, deg, ss, eps, scale, shiftb, P1, n);
            k_mlp<256, 256, 256><<<gx, 512, 0, stream>>>(P1, wh[2], b1, wh[3], b2, P0, partial, n);
        } else {
            k_agg16<256, true><<<(n + 7) / 8, 256, 0, stream>>>(
                P0, rowp, deg, ss, eps, scale, shiftb, P1, n);
            k_mlp<256, 128, 128><<<gx, 512, 0, stream>>>(P1, wh[4], b1, wh[5], b2, P0, partial, n);
        }

        if (Mout == 256) k_bnred<256><<<64, 256, 0, stream>>>(partial, gamma, beta, scale, shiftb, n, gx * 2);
        else             k_bnred<128><<<32, 256, 0, stream>>>(partial, gamma, beta, scale, shiftb, n, gx * 2);
    }

    // ---- readout (applies layer-2 BN affine) ----
    hipMemsetAsync(gsum, 0, NG * 128 * sizeof(float), stream);
    hipMemsetAsync(gcnt, 0, NG * sizeof(int), stream);
    k_readout_bn<<<256, 256, 0, stream>>>(P0, scale, shiftb, gid, gsum, gcnt, n);
    k_final<<<4, 256, 0, stream>>>(gsum, gcnt, (float*)d_out);
}

// Round 6
// 516.408 us; speedup vs baseline: 1.7518x; 1.0156x over previous
//
#include <hip/hip_runtime.h>

#define NG 8   // graphs

typedef _Float16 half8 __attribute__((ext_vector_type(8)));
typedef float    f32x4 __attribute__((ext_vector_type(4)));

// ---------------- casts ----------------

__global__ __launch_bounds__(256)
void k_cast16(const float* __restrict__ in, _Float16* __restrict__ out, int n8) {
    int i = blockIdx.x * 256 + threadIdx.x;
    if (i < n8) {
        const float4 a = *(const float4*)(in + (size_t)i * 8);
        const float4 b = *(const float4*)(in + (size_t)i * 8 + 4);
        half8 o;
        o[0] = (_Float16)a.x; o[1] = (_Float16)a.y; o[2] = (_Float16)a.z; o[3] = (_Float16)a.w;
        o[4] = (_Float16)b.x; o[5] = (_Float16)b.y; o[6] = (_Float16)b.z; o[7] = (_Float16)b.w;
        *(half8*)(out + (size_t)i * 8) = o;
    }
}

// ---------------- CSR build ----------------

__global__ __launch_bounds__(256)
void k_deg(const int* __restrict__ dst, int* __restrict__ deg, int E) {
    int i = blockIdx.x * 256 + threadIdx.x;
    if (i < E) atomicAdd(&deg[dst[i]], 1);
}

__global__ __launch_bounds__(1024)
void k_scan_a(const int* __restrict__ deg, int* __restrict__ incl,
              int* __restrict__ bsum, int n) {
    __shared__ int s[1024];
    int t = threadIdx.x;
    int base = blockIdx.x * 1024;
    int v = (base + t < n) ? deg[base + t] : 0;
    s[t] = v;
    __syncthreads();
    for (int off = 1; off < 1024; off <<= 1) {
        int x = 0;
        if (t >= off) x = s[t - off];
        __syncthreads();
        if (t >= off) s[t] += x;
        __syncthreads();
    }
    if (base + t < n) incl[base + t] = s[t];
    if (t == 1023) bsum[blockIdx.x] = s[1023];
}

__global__ void k_scan_b(int* bsum, int nb) {
    if (threadIdx.x == 0 && blockIdx.x == 0) {
        int run = 0;
        for (int i = 0; i < nb; ++i) { int v = bsum[i]; bsum[i] = run; run += v; }
    }
}

__global__ __launch_bounds__(256)
void k_scan_c(const int* __restrict__ incl, const int* __restrict__ deg,
              const int* __restrict__ bsum, int* __restrict__ rowp, int n) {
    int i = blockIdx.x * 256 + threadIdx.x;
    if (i < n) rowp[i] = incl[i] - deg[i] + bsum[i >> 10];
}

__global__ __launch_bounds__(256)
void k_scatter(const int* __restrict__ src, const int* __restrict__ dst,
               const int* __restrict__ rowp, int* __restrict__ cur,
               int* __restrict__ ss, int E) {
    int i = blockIdx.x * 256 + threadIdx.x;
    if (i < E) {
        int d = dst[i];
        int pos = rowp[d] + atomicAdd(&cur[d], 1);
        ss[pos] = src[i];
    }
}

// ---------------- aggregation (fp16 rows, fp32 accum), fused BN-apply+ReLU ----------------

template<int K, bool AFFINE>
__global__ __launch_bounds__(256)
void k_agg16(const _Float16* __restrict__ h, const int* __restrict__ rowp,
             const int* __restrict__ deg, const int* __restrict__ ss,
             const float* __restrict__ eps, const float* __restrict__ scp,
             const float* __restrict__ shp, _Float16* __restrict__ z, int n) {
    constexpr int TPN = K / 8;
    constexpr int NPB = 256 / TPN;
    int node = blockIdx.x * NPB + threadIdx.x / TPN;
    int lane = threadIdx.x % TPN;
    if (node >= n) return;
    float e1 = 1.0f + eps[0];
    const int c0 = lane * 8;
    float sc[8], sh[8];
    if (AFFINE) {
#pragma unroll
        for (int e = 0; e < 8; ++e) { sc[e] = scp[c0 + e]; sh[e] = shp[c0 + e]; }
    }
    size_t base = (size_t)node * K + c0;
    half8 v = *(const half8*)(h + base);
    float a[8];
#pragma unroll
    for (int e = 0; e < 8; ++e) {
        float f = (float)v[e];
        if (AFFINE) f = fmaxf(f * sc[e] + sh[e], 0.0f);
        a[e] = f * e1;
    }
    int s  = rowp[node];
    int dn = deg[node];
    int j = 0;
    for (; j + 4 <= dn; j += 4) {
        int u0 = ss[s + j], u1 = ss[s + j + 1], u2 = ss[s + j + 2], u3 = ss[s + j + 3];
        half8 h0 = *(const half8*)(h + (size_t)u0 * K + c0);
        half8 h1 = *(const half8*)(h + (size_t)u1 * K + c0);
        half8 h2 = *(const half8*)(h + (size_t)u2 * K + c0);
        half8 h3 = *(const half8*)(h + (size_t)u3 * K + c0);
#pragma unroll
        for (int e = 0; e < 8; ++e) {
            float f0 = (float)h0[e], f1 = (float)h1[e];
            float f2 = (float)h2[e], f3 = (float)h3[e];
            if (AFFINE) {
                f0 = fmaxf(f0 * sc[e] + sh[e], 0.0f);
                f1 = fmaxf(f1 * sc[e] + sh[e], 0.0f);
                f2 = fmaxf(f2 * sc[e] + sh[e], 0.0f);
                f3 = fmaxf(f3 * sc[e] + sh[e], 0.0f);
            }
            a[e] += (f0 + f1) + (f2 + f3);
        }
    }
    for (; j < dn; ++j) {
        int u = ss[s + j];
        half8 hv = *(const half8*)(h + (size_t)u * K + c0);
#pragma unroll
        for (int e = 0; e < 8; ++e) {
            float f = (float)hv[e];
            if (AFFINE) f = fmaxf(f * sc[e] + sh[e], 0.0f);
            a[e] += f;
        }
    }
    half8 o;
#pragma unroll
    for (int e = 0; e < 8; ++e) o[e] = (_Float16)a[e];
    *(half8*)(z + base) = o;
}

// ---------------- fused MLP: C = (A@W1^T+b1).relu() @ W2^T + b2, + BN partials ----------------
// A: [n x K] fp16; W1: [MID x K] fp16; W2: [MOUT x MID] fp16.
// One block = 64 rows, 512 threads (8 waves, 2 row-halves x 4 col-quarters).
// Y (64 x MID) lives in LDS between the two GEMMs. No global atomics:
// per-(block, row-half) BN partials at partial[(bid*2+wr)*2*MOUT + {c, MOUT+c}].

template<int K, int MID, int MOUT>
__global__ __launch_bounds__(512)
void k_mlp(const _Float16* __restrict__ A, const _Float16* __restrict__ W1,
           const float* __restrict__ b1, const _Float16* __restrict__ W2,
           const float* __restrict__ b2, _Float16* __restrict__ C,
           float* __restrict__ partial, int n) {
    constexpr int FN1 = MID / 64, WC1 = 16 * FN1;
    constexpr int FN2 = MOUT / 64, WC2 = 16 * FN2;
    constexpr int BI1 = MID / 64;    // W1 staging issues per k-step
    constexpr int BI2 = MOUT / 64;   // W2 staging issues per k-step
    __shared__ char smem[8192 + 32768 + MID * 128];
    char* As = smem;                 // [64][128B]
    char* Ws = smem + 8192;          // [max rows][128B] (W1, then W2)
    char* Ys = smem + 8192 + 32768;  // [64][MID*2 B], XOR-swizzled
    const int tid  = threadIdx.x;
    const int lane = tid & 63;
    const int wid  = tid >> 6;
    const int wr   = wid >> 2;       // 0..1
    const int wc   = wid & 3;        // 0..3
    const int brow = blockIdx.x * 64;
    const int srow = tid >> 3;       // 0..63
    const int spk  = (tid & 7) << 4; // 0..112
    const int lkA  = spk ^ ((srow & 7) << 4);

    // ================= phase 1: Y = relu(A @ W1^T + b1) =================
    f32x4 acc1[2][FN1];
#pragma unroll
    for (int m = 0; m < 2; ++m)
#pragma unroll
        for (int nn = 0; nn < FN1; ++nn) acc1[m][nn] = (f32x4){0.f, 0.f, 0.f, 0.f};

    uint4 ar, wr1[BI1];
    const int nk1 = K >> 6;
    {
        int ga = brow + srow; if (ga > n - 1) ga = n - 1;
        ar = *(const uint4*)((const char*)A + ((size_t)ga * K) * 2 + lkA);
#pragma unroll
        for (int i = 0; i < BI1; ++i)
            wr1[i] = *(const uint4*)((const char*)W1 + ((size_t)(i * 64 + srow) * K) * 2 + lkA);
    }
    for (int t = 0; t < nk1; ++t) {
        __syncthreads();
        *(uint4*)(As + srow * 128 + spk) = ar;
#pragma unroll
        for (int i = 0; i < BI1; ++i)
            *(uint4*)(Ws + (i * 64 + srow) * 128 + spk) = wr1[i];
        __syncthreads();
        if (t + 1 < nk1) {
            int k0 = (t + 1) << 6;
            int ga = brow + srow; if (ga > n - 1) ga = n - 1;
            ar = *(const uint4*)((const char*)A + ((size_t)ga * K + k0) * 2 + lkA);
#pragma unroll
            for (int i = 0; i < BI1; ++i)
                wr1[i] = *(const uint4*)((const char*)W1 + ((size_t)(i * 64 + srow) * K + k0) * 2 + lkA);
        }
#pragma unroll
        for (int kk = 0; kk < 2; ++kk) {
            const int kb = kk * 64 + (lane >> 4) * 16;
            half8 af[2], bf[FN1];
#pragma unroll
            for (int m = 0; m < 2; ++m) {
                int rowA = wr * 32 + m * 16 + (lane & 15);
                af[m] = *(const half8*)(As + rowA * 128 + (kb ^ ((rowA & 7) << 4)));
            }
#pragma unroll
            for (int nn = 0; nn < FN1; ++nn) {
                int rowB = wc * WC1 + nn * 16 + (lane & 15);
                bf[nn] = *(const half8*)(Ws + rowB * 128 + (kb ^ ((rowB & 7) << 4)));
            }
#pragma unroll
            for (int m = 0; m < 2; ++m)
#pragma unroll
                for (int nn = 0; nn < FN1; ++nn)
                    acc1[m][nn] = __builtin_amdgcn_mfma_f32_16x16x32_f16(af[m], bf[nn], acc1[m][nn], 0, 0, 0);
        }
    }

    // bias + relu -> Ys (fp16, swizzled)
    {
        float bb1[FN1];
#pragma unroll
        for (int nn = 0; nn < FN1; ++nn) bb1[nn] = b1[wc * WC1 + nn * 16 + (lane & 15)];
#pragma unroll
        for (int m = 0; m < 2; ++m)
#pragma unroll
            for (int nn = 0; nn < FN1; ++nn)
#pragma unroll
                for (int j = 0; j < 4; ++j) {
                    int row = wr * 32 + m * 16 + (lane >> 4) * 4 + j;
                    int col = wc * WC1 + nn * 16 + (lane & 15);
                    float v = fmaxf(acc1[m][nn][j] + bb1[nn], 0.0f);
                    *(_Float16*)(Ys + row * (MID * 2) + ((col * 2) ^ ((row & 7) << 4))) = (_Float16)v;
                }
    }

    // ================= phase 2: C = Y @ W2^T + b2 =================
    f32x4 acc2[2][FN2];
#pragma unroll
    for (int m = 0; m < 2; ++m)
#pragma unroll
        for (int nn = 0; nn < FN2; ++nn) acc2[m][nn] = (f32x4){0.f, 0.f, 0.f, 0.f};

    uint4 wr2[BI2];
#pragma unroll
    for (int i = 0; i < BI2; ++i)
        wr2[i] = *(const uint4*)((const char*)W2 + ((size_t)(i * 64 + srow) * MID) * 2 + lkA);

    const int nk2 = MID >> 6;
    for (int t = 0; t < nk2; ++t) {
        __syncthreads();   // t=0: Y visible + W1 reads done; t>0: prior W2 reads done
#pragma unroll
        for (int i = 0; i < BI2; ++i)
            *(uint4*)(Ws + (i * 64 + srow) * 128 + spk) = wr2[i];
        __syncthreads();
        if (t + 1 < nk2) {
            int k0 = (t + 1) << 6;
#pragma unroll
            for (int i = 0; i < BI2; ++i)
                wr2[i] = *(const uint4*)((const char*)W2 + ((size_t)(i * 64 + srow) * MID + k0) * 2 + lkA);
        }
#pragma unroll
        for (int kk = 0; kk < 2; ++kk) {
            const int kb = kk * 64 + (lane >> 4) * 16;
            half8 af[2], bf[FN2];
#pragma unroll
            for (int m = 0; m < 2; ++m) {
                int rowA = wr * 32 + m * 16 + (lane & 15);
                af[m] = *(const half8*)(Ys + rowA * (MID * 2) + ((t * 128 + kb) ^ ((rowA & 7) << 4)));
            }
#pragma unroll
            for (int nn = 0; nn < FN2; ++nn) {
                int rowB = wc * WC2 + nn * 16 + (lane & 15);
                bf[nn] = *(const half8*)(Ws + rowB * 128 + (kb ^ ((rowB & 7) << 4)));
            }
#pragma unroll
            for (int m = 0; m < 2; ++m)
#pragma unroll
                for (int nn = 0; nn < FN2; ++nn)
                    acc2[m][nn] = __builtin_amdgcn_mfma_f32_16x16x32_f16(af[m], bf[nn], acc2[m][nn], 0, 0, 0);
        }
    }

    // ================= epilogue: coalesced store + BN partials =================
    __syncthreads();   // Ws/As reads done; reuse smem as transpose buffers
    char* tb = smem + wid * 2304;   // per-wave [16][72] fp16 (144 B row stride)
    const int colbase = wc * WC2;
    float bb2[FN2];
#pragma unroll
    for (int nn = 0; nn < FN2; ++nn) bb2[nn] = b2[colbase + nn * 16 + (lane & 15)];
    constexpr int GRP = FN2 * 2;
    constexpr int RPI = 64 / GRP;
    constexpr int NIT = 16 / RPI;
    const int g    = lane & (GRP - 1);
    const int rl   = lane / GRP;
    const int rcol = colbase + g * 8;
    const int rowbase = brow + wr * 32;
    float s[8], q[8];
#pragma unroll
    for (int e = 0; e < 8; ++e) { s[e] = 0.f; q[e] = 0.f; }
#pragma unroll
    for (int m = 0; m < 2; ++m) {
#pragma unroll
        for (int nn = 0; nn < FN2; ++nn)
#pragma unroll
            for (int j = 0; j < 4; ++j) {
                float v = acc2[m][nn][j] + bb2[nn];
                *(_Float16*)(tb + ((lane >> 4) * 4 + j) * 144 + (nn * 16 + (lane & 15)) * 2) = (_Float16)v;
            }
#pragma unroll
        for (int it = 0; it < NIT; ++it) {
            int lr = it * RPI + rl;
            int grow = rowbase + m * 16 + lr;
            half8 v = *(const half8*)(tb + lr * 144 + g * 16);
            if (grow < n) {
                *(half8*)(C + (size_t)grow * MOUT + rcol) = v;
#pragma unroll
                for (int e = 0; e < 8; ++e) { float f = (float)v[e]; s[e] += f; q[e] += f * f; }
            }
        }
    }
#pragma unroll
    for (int e = 0; e < 8; ++e) {
        for (int mk = GRP; mk < 64; mk <<= 1) {
            s[e] += __shfl_xor(s[e], mk, 64);
            q[e] += __shfl_xor(q[e], mk, 64);
        }
    }
    if (lane < GRP) {
        float* p = partial + ((size_t)blockIdx.x * 2 + wr) * 2 * MOUT;
#pragma unroll
        for (int e = 0; e < 8; ++e) {
            p[rcol + e]        = s[e];
            p[MOUT + rcol + e] = q[e];
        }
    }
}

// ---------------- BN reduce: partial rows -> scale/shift ----------------
// grid = M/4 blocks x 256 threads (1 wave per column).

template<int M>
__global__ __launch_bounds__(256)
void k_bnred(const float* __restrict__ partial, const float* __restrict__ gamma,
             const float* __restrict__ beta, float* __restrict__ scale,
             float* __restrict__ shift, int n, int nrows) {
    const int w = threadIdx.x >> 6, lane = threadIdx.x & 63;
    const int c = blockIdx.x * 4 + w;
    float s = 0.f, q = 0.f;
    for (int b = lane; b < nrows; b += 64) {
        s += partial[(size_t)b * 2 * M + c];
        q += partial[(size_t)b * 2 * M + M + c];
    }
#pragma unroll
    for (int mk = 1; mk < 64; mk <<= 1) {
        s += __shfl_xor(s, mk, 64);
        q += __shfl_xor(q, mk, 64);
    }
    if (lane == 0) {
        float invN = 1.0f / (float)n;
        float mean = s * invN;
        float var  = q * invN - mean * mean;
        float sc   = rsqrtf(var + 1e-5f) * gamma[c];
        scale[c] = sc;
        shift[c] = beta[c] - mean * sc;
    }
}

// ---------------- graph readout (fused final BN affine) ----------------

__global__ __launch_bounds__(256)
void k_readout_bn(const _Float16* __restrict__ z, const float* __restrict__ scale,
                  const float* __restrict__ shift, const int* __restrict__ gid,
                  float* __restrict__ gsum, int* __restrict__ gcnt, int n) {
    __shared__ float ls[NG * 128];
    __shared__ int   lc[NG];
    for (int i = threadIdx.x; i < NG * 128; i += 256) ls[i] = 0.0f;
    if (threadIdx.x < NG) lc[threadIdx.x] = 0;
    __syncthreads();
    int c  = threadIdx.x & 127;
    int ro = threadIdx.x >> 7;
    const float sc = scale[c];
    const float sh = shift[c];
    for (int r = blockIdx.x * 2 + ro; r < n; r += gridDim.x * 2) {
        int g = gid[r];
        float v = (float)z[(size_t)r * 128 + c] * sc + sh;
        atomicAdd(&ls[g * 128 + c], v);
        if (c == 0) atomicAdd(&lc[g], 1);
    }
    __syncthreads();
    for (int i = threadIdx.x; i < NG * 128; i += 256) atomicAdd(&gsum[i], ls[i]);
    if (threadIdx.x < NG) atomicAdd(&gcnt[threadIdx.x], lc[threadIdx.x]);
}

__global__ void k_final(const float* __restrict__ gsum, const int* __restrict__ gcnt,
                        float* __restrict__ out) {
    int i = blockIdx.x * 256 + threadIdx.x;
    if (i < NG * 128) {
        int g = i >> 7;
        out[i] = gsum[i] / fmaxf((float)gcnt[g], 1.0f);
    }
}

// ---------------- host ----------------

extern "C" void kernel_launch(void* const* d_in, const int* in_sizes, int n_in,
                              void* d_out, int out_size, void* d_ws, size_t ws_size,
                              hipStream_t stream) {
    const float* x   = (const float*)d_in[0];
    const int*   src = (const int*)d_in[1];
    const int*   dst = (const int*)d_in[2];
    const int*   gid = (const int*)d_in[3];
    const int n = in_sizes[0] / 128;
    const int E = in_sizes[1];

    auto align = [](size_t o) { return (o + 255) & ~(size_t)255; };
    char* ws = (char*)d_ws;
    size_t off = 0;
    const size_t SZ_H = align((size_t)n * 256 * sizeof(_Float16));
    const size_t SZ_I = align((size_t)n * sizeof(int));
    const int gx = (n + 63) / 64;

    _Float16* h0 = (_Float16*)(ws + off); off += align((size_t)n * 128 * sizeof(_Float16));
    _Float16* P0 = (_Float16*)(ws + off); off += SZ_H;
    _Float16* P1 = (_Float16*)(ws + off); off += SZ_H;
    int*   deg  = (int*)(ws + off);   off += SZ_I;
    int*   incl = (int*)(ws + off);   off += SZ_I;
    int*   rowp = (int*)(ws + off);   off += SZ_I;
    int*   cur  = (int*)(ws + off);   off += SZ_I;
    int*   bsum = (int*)(ws + off);   off += 256 * sizeof(int);
    int*   ss   = (int*)(ws + off);   off += align((size_t)E * sizeof(int));
    float* partial = (float*)(ws + off); off += align((size_t)gx * 2 * 2 * 256 * sizeof(float));
    float* scale   = (float*)(ws + off); off += align(256 * sizeof(float));
    float* shiftb  = (float*)(ws + off); off += align(256 * sizeof(float));
    float* gsum = (float*)(ws + off); off += align(NG * 128 * sizeof(float));
    int*   gcnt = (int*)(ws + off);   off += align(NG * sizeof(int));
    _Float16* wh[6];
    for (int i = 0; i < 6; ++i) { wh[i] = (_Float16*)(ws + off); off += align(65536 * sizeof(_Float16)); }

    const int Ks[3]    = {128, 256, 256};
    const int Mids[3]  = {256, 256, 128};
    const int Mouts[3] = {256, 256, 128};

    // ---- casts ----
    k_cast16<<<(n * 128 / 8 + 255) / 256, 256, 0, stream>>>(x, h0, n * 128 / 8);
    for (int L = 0; L < 3; ++L) {
        const int base = 4 + 7 * L;
        int n1 = Mids[L] * Ks[L];
        int n2 = Mouts[L] * Mids[L];
        k_cast16<<<(n1 / 8 + 255) / 256, 256, 0, stream>>>((const float*)d_in[base + 0], wh[2 * L + 0], n1 / 8);
        k_cast16<<<(n2 / 8 + 255) / 256, 256, 0, stream>>>((const float*)d_in[base + 2], wh[2 * L + 1], n2 / 8);
    }

    // ---- CSR build (dst-keyed) ----
    hipMemsetAsync(deg, 0, (size_t)n * sizeof(int), stream);
    k_deg<<<(E + 255) / 256, 256, 0, stream>>>(dst, deg, E);
    int nb = (n + 1023) / 1024;
    k_scan_a<<<nb, 1024, 0, stream>>>(deg, incl, bsum, n);
    k_scan_b<<<1, 1, 0, stream>>>(bsum, nb);
    k_scan_c<<<(n + 255) / 256, 256, 0, stream>>>(incl, deg, bsum, rowp, n);
    hipMemsetAsync(cur, 0, (size_t)n * sizeof(int), stream);
    k_scatter<<<(E + 255) / 256, 256, 0, stream>>>(src, dst, rowp, cur, ss, E);

    // ---- layers ----
    for (int L = 0; L < 3; ++L) {
        const int base = 4 + 7 * L;
        const float* b1    = (const float*)d_in[base + 1];
        const float* b2    = (const float*)d_in[base + 3];
        const float* eps   = (const float*)d_in[base + 4];
        const float* gamma = (const float*)d_in[base + 5];
        const float* beta  = (const float*)d_in[base + 6];
        const int Mout = Mouts[L];

        if (L == 0) {
            k_agg16<128, false><<<(n + 15) / 16, 256, 0, stream>>>(
                h0, rowp, deg, ss, eps, nullptr, nullptr, P1, n);
            k_mlp<128, 256, 256><<<gx, 512, 0, stream>>>(P1, wh[0], b1, wh[1], b2, P0, partial, n);
        } else if (L == 1) {
            k_agg16<256, true><<<(n + 7) / 8, 256, 0, stream>>>(
                P0, rowp, deg, ss, eps, scale, shiftb, P1, n);
            k_mlp<256, 256, 256><<<gx, 512, 0, stream>>>(P1, wh[2], b1, wh[3], b2, P0, partial, n);
        } else {
            k_agg16<256, true><<<(n + 7) / 8, 256, 0, stream>>>(
                P0, rowp, deg, ss, eps, scale, shiftb, P1, n);
            k_mlp<256, 128, 128><<<gx, 512, 0, stream>>>(P1, wh[4], b1, wh[5], b2, P0, partial, n);
        }

        if (Mout == 256) k_bnred<256><<<64, 256, 0, stream>>>(partial, gamma, beta, scale, shiftb, n, gx * 2);
        else             k_bnred<128><<<32, 256, 0, stream>>>(partial, gamma, beta, scale, shiftb, n, gx * 2);
    }

    // ---- readout (applies layer-2 BN affine) ----
    hipMemsetAsync(gsum, 0, NG * 128 * sizeof(float), stream);
    hipMemsetAsync(gcnt, 0, NG * sizeof(int), stream);
    k_readout_bn<<<256, 256, 0, stream>>>(P0, scale, shiftb, gid, gsum, gcnt, n);
    k_final<<<4, 256, 0, stream>>>(gsum, gcnt, (float*)d_out);
}